// Round 1
// baseline (374.268 us; speedup 1.0000x reference)
//
#include <hip/hip_runtime.h>
#include <hip/hip_bf16.h>

// Sparse (Minkowski) conv: gather -> per-offset GEMM (bf16 MFMA) -> scatter-add.
// x: [N=262144, 64] f32, W: [27, 64, 64] f32, in_map/out_map: [27, 65536] i32.
// out: [262144, 64] f32, accumulated via fp32 atomics.

typedef __attribute__((ext_vector_type(8))) short bf16x8;  // 8 bf16 in 4 VGPRs
typedef __attribute__((ext_vector_type(4))) float f32x4;

constexpr int KOFF = 27;
constexpr int M = 65536;
constexpr int CIN = 64;
constexpr int COUT = 64;
constexpr int TM_BLOCK = 512;                 // m rows per block
constexpr int TILES_PER_K = M / TM_BLOCK;     // 128
constexpr int SUBTILES = TM_BLOCK / (4 * 16); // 8 subtiles of 16 rows per wave

// f32 -> bf16 round-to-nearest-even
static __device__ __forceinline__ short f2bf(float f) {
  unsigned u = __builtin_bit_cast(unsigned, f);
  unsigned r = (u + 0x7FFFu + ((u >> 16) & 1u)) >> 16;
  return (short)r;
}

static __device__ __forceinline__ bf16x8 pack8(float4 p, float4 q) {
  bf16x8 r;
  r[0] = f2bf(p.x); r[1] = f2bf(p.y); r[2] = f2bf(p.z); r[3] = f2bf(p.w);
  r[4] = f2bf(q.x); r[5] = f2bf(q.y); r[6] = f2bf(q.z); r[7] = f2bf(q.w);
  return r;
}

__global__ __launch_bounds__(256) void spconv_mfma_kernel(
    const float* __restrict__ x, const float* __restrict__ W,
    const int* __restrict__ in_map, const int* __restrict__ out_map,
    float* __restrict__ out) {
  const int k = blockIdx.x / TILES_PER_K;
  const int mblock = (blockIdx.x % TILES_PER_K) * TM_BLOCK;
  const int wave = threadIdx.x >> 6;
  const int l = threadIdx.x & 63;
  const int g = l >> 4;   // 0..3 (16-lane group)
  const int lr = l & 15;  // 0..15

  // --- B fragments from W[k]: bfrag[t][u][j] = W[k][u*32 + g*8 + j][t*16 + lr]
  // (B layout for mfma_f32_16x16x32_bf16: lane holds B[kk=(l>>4)*8+j][col=l&15])
  // Loaded once per wave, L2-hot (W[k] is 16 KB, reused by 128 blocks).
  bf16x8 bfrag[4][2];
  const float* Wk = W + k * (CIN * COUT);
#pragma unroll
  for (int t = 0; t < 4; ++t) {
#pragma unroll
    for (int u = 0; u < 2; ++u) {
#pragma unroll
      for (int j = 0; j < 8; ++j) {
        bfrag[t][u][j] = f2bf(Wk[(u * 32 + g * 8 + j) * COUT + t * 16 + lr]);
      }
    }
  }

  const int mwave = mblock + wave * (TM_BLOCK / 4);
#pragma unroll 1
  for (int s = 0; s < SUBTILES; ++s) {
    const int mbase = mwave + s * 16;

    // --- A fragments: lane holds A[row=lr][c=g*8+j] (u=0) and c+32 (u=1).
    // Gathered row: two float4 per c-half, 32B-aligned.
    const int in_idx = in_map[k * M + mbase + lr];
    const float* xr = x + (size_t)in_idx * CIN + g * 8;
    float4 x0 = *(const float4*)(xr);
    float4 x1 = *(const float4*)(xr + 4);
    float4 x2 = *(const float4*)(xr + 32);
    float4 x3 = *(const float4*)(xr + 36);
    bf16x8 a0 = pack8(x0, x1);
    bf16x8 a1 = pack8(x2, x3);

    // --- MFMA: acc[t] = A(16x64) @ W[k][:, t*16:(t+1)*16]
    f32x4 acc[4] = {{0.f, 0.f, 0.f, 0.f}, {0.f, 0.f, 0.f, 0.f},
                    {0.f, 0.f, 0.f, 0.f}, {0.f, 0.f, 0.f, 0.f}};
#pragma unroll
    for (int t = 0; t < 4; ++t) {
      acc[t] = __builtin_amdgcn_mfma_f32_16x16x32_bf16(a0, bfrag[t][0], acc[t], 0, 0, 0);
      acc[t] = __builtin_amdgcn_mfma_f32_16x16x32_bf16(a1, bfrag[t][1], acc[t], 0, 0, 0);
    }

    // --- Scatter-add. D layout: lane holds D[row=(l>>4)*4+r][col=l&15].
    const int obase = k * M + mbase + g * 4;
    int oidx[4];
#pragma unroll
    for (int r = 0; r < 4; ++r) oidx[r] = out_map[obase + r];
#pragma unroll
    for (int t = 0; t < 4; ++t) {
#pragma unroll
      for (int r = 0; r < 4; ++r) {
        atomicAdd(out + (size_t)oidx[r] * COUT + t * 16 + lr, acc[t][r]);
      }
    }
  }
}

extern "C" void kernel_launch(void* const* d_in, const int* in_sizes, int n_in,
                              void* d_out, int out_size, void* d_ws, size_t ws_size,
                              hipStream_t stream) {
  const float* x = (const float*)d_in[0];
  const float* W = (const float*)d_in[1];
  const int* in_map = (const int*)d_in[2];
  const int* out_map = (const int*)d_in[3];
  float* out = (float*)d_out;

  // Atomics accumulate into d_out -> must zero it every launch.
  hipMemsetAsync(d_out, 0, (size_t)out_size * sizeof(float), stream);

  dim3 grid(KOFF * TILES_PER_K);
  spconv_mfma_kernel<<<grid, dim3(256), 0, stream>>>(x, W, in_map, out_map, out);
}